// Round 1
// baseline (1414.010 us; speedup 1.0000x reference)
//
#include <hip/hip_runtime.h>

#define NN 50000
#define EE 800000
#define INF 32
#define PEF 15
#define HID 128
#define GG 64
#define NLAYERS 4

__device__ __forceinline__ float wave_allsum(float v) {
  #pragma unroll
  for (int off = 1; off < 64; off <<= 1) v += __shfl_xor(v, off);
  return v;
}

// ---------------- weight packing ----------------
__global__ void pack_weights_kernel(const float* __restrict__ Wq, const float* __restrict__ Wk,
                                    const float* __restrict__ Wv, const float* __restrict__ Ws,
                                    const float* __restrict__ bq, const float* __restrict__ bk,
                                    const float* __restrict__ bv, const float* __restrict__ bs,
                                    float* __restrict__ Wcat, float* __restrict__ bcat) {
  int idx = blockIdx.x * blockDim.x + threadIdx.x;
  if (idx >= 512 * 128) return;
  int o = idx >> 7, j = idx & 127;
  int w = o >> 7, r = o & 127;
  const float* W = (w == 0) ? Wq : (w == 1) ? Wk : (w == 2) ? Wv : Ws;
  Wcat[idx] = W[r * 128 + j];
  if (j == 0) {
    const float* b = (w == 0) ? bq : (w == 1) ? bk : (w == 2) ? bv : bs;
    bcat[o] = b[r];
  }
}

__global__ void pack_nwt_kernel(const float* __restrict__ niw, float* __restrict__ nwT) {
  int idx = blockIdx.x * blockDim.x + threadIdx.x;
  if (idx >= 47 * 128) return;
  int j = idx >> 7, o = idx & 127;
  nwT[j * 128 + o] = niw[o * 47 + j];
}

// ---------------- node_in: h = [x|pe] @ W^T + b ----------------
__global__ __launch_bounds__(256) void nodein_kernel(const float* __restrict__ x,
    const float* __restrict__ pe, const float* __restrict__ nwT,
    const float* __restrict__ bias, float* __restrict__ h) {
  int wv = blockIdx.x * 4 + (threadIdx.x >> 6);
  if (wv >= NN) return;
  int lane = threadIdx.x & 63;
  float acc0 = bias[lane], acc1 = bias[64 + lane];
  const float* xr = x + (size_t)wv * INF;
  const float* pr = pe + (size_t)wv * PEF;
  #pragma unroll
  for (int j = 0; j < INF; j++) {
    float f = xr[j];
    acc0 += f * nwT[j * 128 + lane];
    acc1 += f * nwT[j * 128 + 64 + lane];
  }
  #pragma unroll
  for (int j = 0; j < PEF; j++) {
    float f = pr[j];
    acc0 += f * nwT[(INF + j) * 128 + lane];
    acc1 += f * nwT[(INF + j) * 128 + 64 + lane];
  }
  h[(size_t)wv * 128 + lane] = acc0;
  h[(size_t)wv * 128 + 64 + lane] = acc1;
}

// ---------------- CSR build ----------------
__global__ void count_kernel(const int* __restrict__ dst, int* __restrict__ counts) {
  int e = blockIdx.x * blockDim.x + threadIdx.x;
  if (e >= EE) return;
  atomicAdd(&counts[dst[e]], 1);
}

__global__ __launch_bounds__(1024) void scan_kernel(const int* __restrict__ counts,
    int* __restrict__ row_ptr, int* __restrict__ cursor) {
  __shared__ int wsum[16];
  __shared__ int carry_s;
  int t = threadIdx.x;
  int lane = t & 63, wid = t >> 6;
  if (t == 0) { carry_s = 0; row_ptr[0] = 0; }
  __syncthreads();
  for (int base = 0; base < NN; base += 1024) {
    int i = base + t;
    int v = (i < NN) ? counts[i] : 0;
    int xv = v;
    #pragma unroll
    for (int off = 1; off < 64; off <<= 1) {
      int u = __shfl_up(xv, off);
      if (lane >= off) xv += u;
    }
    if (lane == 63) wsum[wid] = xv;
    __syncthreads();
    if (wid == 0) {
      int w = (lane < 16) ? wsum[lane] : 0;
      #pragma unroll
      for (int off = 1; off < 16; off <<= 1) {
        int u = __shfl_up(w, off);
        if (lane >= off) w += u;
      }
      if (lane < 16) wsum[lane] = w;
    }
    __syncthreads();
    int offset = carry_s + (wid > 0 ? wsum[wid - 1] : 0);
    int incl = xv + offset;
    if (i < NN) { row_ptr[i + 1] = incl; cursor[i] = incl - v; }
    __syncthreads();
    if (t == 1023) carry_s = incl;
    __syncthreads();
  }
}

__global__ void scatter_kernel(const int* __restrict__ src, const int* __restrict__ dst,
                               int* __restrict__ cursor, int* __restrict__ srcs) {
  int e = blockIdx.x * blockDim.x + threadIdx.x;
  if (e >= EE) return;
  int d = dst[e];
  int p = atomicAdd(&cursor[d], 1);
  srcs[p] = src[e];
}

__global__ void gptr_kernel(const int* __restrict__ batch, int* __restrict__ gptr) {
  int g = threadIdx.x;
  if (g > GG) return;
  if (g == GG) { gptr[GG] = NN; return; }
  int lo = 0, hi = NN;
  while (lo < hi) {
    int mid = (lo + hi) >> 1;
    if (batch[mid] < g) lo = mid + 1; else hi = mid;
  }
  gptr[g] = lo;
}

// ---------------- GEMM: C[M,NO] = A[M,128] @ B[NO,128]^T + bias ----------------
__global__ __launch_bounds__(256) void gemm_bias_kernel(const float* __restrict__ A,
    const float* __restrict__ B, const float* __restrict__ bias,
    float* __restrict__ C, int M, int NO, int ldc, int dorelu) {
  __shared__ float As[32][68];
  __shared__ float Bs[32][68];
  const int t = threadIdx.x;
  const int tx = t & 15, ty = t >> 4;
  const int m0 = blockIdx.x * 64, n0 = blockIdx.y * 64;
  const int lrow = t >> 2;        // 0..63
  const int lkc = (t & 3) * 8;    // 0,8,16,24
  float acc[4][4] = {};
  for (int k0 = 0; k0 < 128; k0 += 32) {
    float4 a0 = {0, 0, 0, 0}, a1 = {0, 0, 0, 0};
    int m = m0 + lrow;
    if (m < M) {
      const float4* ap = (const float4*)(A + (size_t)m * 128 + k0 + lkc);
      a0 = ap[0]; a1 = ap[1];
    }
    const float4* bp = (const float4*)(B + (size_t)(n0 + lrow) * 128 + k0 + lkc);
    float4 b0 = bp[0], b1 = bp[1];
    __syncthreads();
    As[lkc + 0][lrow] = a0.x; As[lkc + 1][lrow] = a0.y;
    As[lkc + 2][lrow] = a0.z; As[lkc + 3][lrow] = a0.w;
    As[lkc + 4][lrow] = a1.x; As[lkc + 5][lrow] = a1.y;
    As[lkc + 6][lrow] = a1.z; As[lkc + 7][lrow] = a1.w;
    Bs[lkc + 0][lrow] = b0.x; Bs[lkc + 1][lrow] = b0.y;
    Bs[lkc + 2][lrow] = b0.z; Bs[lkc + 3][lrow] = b0.w;
    Bs[lkc + 4][lrow] = b1.x; Bs[lkc + 5][lrow] = b1.y;
    Bs[lkc + 6][lrow] = b1.z; Bs[lkc + 7][lrow] = b1.w;
    __syncthreads();
    #pragma unroll
    for (int kk = 0; kk < 32; kk++) {
      float a[4], b[4];
      #pragma unroll
      for (int i = 0; i < 4; i++) a[i] = As[kk][ty * 4 + i];
      #pragma unroll
      for (int j = 0; j < 4; j++) b[j] = Bs[kk][tx * 4 + j];
      #pragma unroll
      for (int i = 0; i < 4; i++)
        #pragma unroll
        for (int j = 0; j < 4; j++) acc[i][j] += a[i] * b[j];
    }
  }
  #pragma unroll
  for (int i = 0; i < 4; i++) {
    int m = m0 + ty * 4 + i;
    if (m >= M) continue;
    #pragma unroll
    for (int j = 0; j < 4; j++) {
      int n = n0 + tx * 4 + j;
      float v = acc[i][j] + bias[n];
      if (dorelu) v = fmaxf(v, 0.f);
      C[(size_t)m * ldc + n] = v;
    }
  }
}

// ---------------- edge attention (CSR, one wave per dst node) ----------------
__global__ __launch_bounds__(256) void attn_kernel(const float* __restrict__ proj,
    const int* __restrict__ row_ptr, const int* __restrict__ srcs,
    float* __restrict__ outb) {
  int wv = blockIdx.x * 4 + (threadIdx.x >> 6);
  if (wv >= NN) return;
  int lane = threadIdx.x & 63;
  const float2 q2 = ((const float2*)(proj + (size_t)wv * 512))[lane];
  int e0 = row_ptr[wv], e1 = row_ptr[wv + 1];
  float denom = 0.f, accx = 0.f, accy = 0.f;
  for (int e = e0; e < e1; e++) {
    int s = srcs[e];
    const float2* kv = (const float2*)(proj + (size_t)s * 512 + 128);
    float2 k2 = kv[lane];
    float2 v2 = kv[64 + lane];
    float p = q2.x * k2.x + q2.y * k2.y;
    p += __shfl_xor(p, 1); p += __shfl_xor(p, 2);
    p += __shfl_xor(p, 4); p += __shfl_xor(p, 8);
    float ex = __expf(p * 0.17677669529663687f);  // 1/sqrt(32)
    denom += ex;
    accx += ex * v2.x;
    accy += ex * v2.y;
  }
  float inv = (e1 > e0) ? 1.0f / denom : 0.f;
  float2 o2;
  o2.x = accx * inv;
  o2.y = accy * inv;
  ((float2*)(outb + (size_t)wv * 128))[lane] = o2;
}

// ---------------- beta-gated residual + relu ----------------
__global__ __launch_bounds__(256) void beta_kernel(float* __restrict__ h,
    const float* __restrict__ proj, const float* __restrict__ outb,
    const float* __restrict__ Wbeta) {
  int wv = blockIdx.x * 4 + (threadIdx.x >> 6);
  if (wv >= NN) return;
  int lane = threadIdx.x & 63;
  float2 o2 = ((const float2*)(outb + (size_t)wv * 128))[lane];
  float2 x2 = ((const float2*)(proj + (size_t)wv * 512 + 384))[lane];
  const float2* wb = (const float2*)Wbeta;
  float2 wo = wb[lane], wx = wb[64 + lane], wd = wb[128 + lane];
  float part = o2.x * wo.x + o2.y * wo.y + x2.x * wx.x + x2.y * wx.y
             + (o2.x - x2.x) * wd.x + (o2.y - x2.y) * wd.y;
  part = wave_allsum(part);
  float beta = 1.f / (1.f + __expf(-part));
  float2* hp = (float2*)(h + (size_t)wv * 128);
  float2 h2 = hp[lane];
  float r0 = h2.x + beta * x2.x + (1.f - beta) * o2.x;
  float r1 = h2.y + beta * x2.y + (1.f - beta) * o2.y;
  h2.x = fmaxf(r0, 0.f);
  h2.y = fmaxf(r1, 0.f);
  hp[lane] = h2;
}

// ---------------- gate: gx = exp(relu(h@g1^T+b1) @ g2^T + b2) ----------------
__global__ __launch_bounds__(256) void gate_kernel(const float* __restrict__ tb,
    const float* __restrict__ g2w, const float* __restrict__ g2b,
    float* __restrict__ gx) {
  int wv = blockIdx.x * 4 + (threadIdx.x >> 6);
  if (wv >= NN) return;
  int lane = threadIdx.x & 63;
  float2 t2 = ((const float2*)(tb + (size_t)wv * 128))[lane];
  float2 w2 = ((const float2*)g2w)[lane];
  float p = t2.x * w2.x + t2.y * w2.y;
  p = wave_allsum(p);
  if (lane == 0) gx[wv] = __expf(p + g2b[0]);
}

// ---------------- per-graph weighted aggregation ----------------
__global__ __launch_bounds__(128) void gagg_kernel(const float* __restrict__ gx,
    const float* __restrict__ h, const int* __restrict__ gptr,
    float* __restrict__ gfeat) {
  int g = blockIdx.x;
  int d = threadIdx.x;
  int n0 = gptr[g], n1 = gptr[g + 1];
  float acc = 0.f, dsum = 0.f;
  for (int n = n0; n < n1; n++) acc += gx[n] * h[(size_t)n * 128 + d];
  for (int n = n0 + d; n < n1; n += 128) dsum += gx[n];
  __shared__ float red[128];
  red[d] = dsum;
  __syncthreads();
  for (int off = 64; off > 0; off >>= 1) {
    if (d < off) red[d] += red[d + off];
    __syncthreads();
  }
  float inv = (red[0] > 0.f) ? 1.f / red[0] : 0.f;
  gfeat[g * 128 + d] = acc * inv;
}

// ---------------- readout ----------------
__global__ __launch_bounds__(128) void readout_kernel(const float* __restrict__ gfeat,
    const float* __restrict__ r1w, const float* __restrict__ r1b,
    const float* __restrict__ r2w, const float* __restrict__ r2b,
    float* __restrict__ out) {
  int g = blockIdx.x;
  int u = threadIdx.x;
  __shared__ float sh[128];
  __shared__ float red[128];
  sh[u] = gfeat[g * 128 + u];
  __syncthreads();
  float tacc = r1b[u];
  for (int j = 0; j < 128; j++) tacc += sh[j] * r1w[u * 128 + j];
  tacc = fmaxf(tacc, 0.f);
  red[u] = tacc * r2w[u];
  __syncthreads();
  for (int off = 64; off > 0; off >>= 1) {
    if (u < off) red[u] += red[u + off];
    __syncthreads();
  }
  if (u == 0) out[g] = red[0] + r2b[0];
}

extern "C" void kernel_launch(void* const* d_in, const int* in_sizes, int n_in,
                              void* d_out, int out_size, void* d_ws, size_t ws_size,
                              hipStream_t stream) {
  (void)in_sizes; (void)n_in; (void)out_size; (void)ws_size;
  const float* x     = (const float*)d_in[0];
  const int*   ei    = (const int*)d_in[1];
  const int*   batch = (const int*)d_in[2];
  const float* pe    = (const float*)d_in[3];
  const float* niw   = (const float*)d_in[4];
  const float* nib   = (const float*)d_in[5];
  const float* Wq    = (const float*)d_in[6];
  const float* bq    = (const float*)d_in[7];
  const float* Wk    = (const float*)d_in[8];
  const float* bk    = (const float*)d_in[9];
  const float* Wv    = (const float*)d_in[10];
  const float* bv    = (const float*)d_in[11];
  const float* Wsk   = (const float*)d_in[12];
  const float* bsk   = (const float*)d_in[13];
  const float* Wbeta = (const float*)d_in[14];
  const float* g1w   = (const float*)d_in[15];
  const float* g1b   = (const float*)d_in[16];
  const float* g2w   = (const float*)d_in[17];
  const float* g2b   = (const float*)d_in[18];
  const float* r1w   = (const float*)d_in[19];
  const float* r1b   = (const float*)d_in[20];
  const float* r2w   = (const float*)d_in[21];
  const float* r2b   = (const float*)d_in[22];
  float* out = (float*)d_out;

  float* ws = (float*)d_ws;
  float* h     = ws; ws += (size_t)NN * 128;
  float* proj  = ws; ws += (size_t)NN * 512;
  float* outb  = ws; ws += (size_t)NN * 128;
  float* Wcat  = ws; ws += 512 * 128;
  float* bcat  = ws; ws += 512;
  float* nwT   = ws; ws += 47 * 128;
  float* gx    = ws; ws += NN;
  float* gfeat = ws; ws += GG * 128;
  int* row_ptr = (int*)ws;
  int* counts  = row_ptr + (NN + 1);
  int* cursor  = counts + NN;
  int* srcs    = cursor + NN;
  int* gptr    = srcs + EE;

  const int* src = ei;
  const int* dst = ei + EE;

  hipMemsetAsync(counts, 0, NN * sizeof(int), stream);
  pack_weights_kernel<<<(512 * 128 + 255) / 256, 256, 0, stream>>>(
      Wq, Wk, Wv, Wsk, bq, bk, bv, bsk, Wcat, bcat);
  pack_nwt_kernel<<<(47 * 128 + 255) / 256, 256, 0, stream>>>(niw, nwT);
  nodein_kernel<<<12500, 256, 0, stream>>>(x, pe, nwT, nib, h);
  count_kernel<<<(EE + 255) / 256, 256, 0, stream>>>(dst, counts);
  scan_kernel<<<1, 1024, 0, stream>>>(counts, row_ptr, cursor);
  scatter_kernel<<<(EE + 255) / 256, 256, 0, stream>>>(src, dst, cursor, srcs);
  gptr_kernel<<<1, 128, 0, stream>>>(batch, gptr);

  for (int l = 0; l < NLAYERS; l++) {
    gemm_bias_kernel<<<dim3(782, 8), 256, 0, stream>>>(h, Wcat, bcat, proj, NN, 512, 512, 0);
    attn_kernel<<<12500, 256, 0, stream>>>(proj, row_ptr, srcs, outb);
    beta_kernel<<<12500, 256, 0, stream>>>(h, proj, outb, Wbeta);
  }

  gemm_bias_kernel<<<dim3(782, 2), 256, 0, stream>>>(h, g1w, g1b, proj, NN, 128, 128, 1);
  gate_kernel<<<12500, 256, 0, stream>>>(proj, g2w, g2b, gx);
  gagg_kernel<<<GG, 128, 0, stream>>>(gx, h, gptr, gfeat);
  readout_kernel<<<GG, 128, 0, stream>>>(gfeat, r1w, r1b, r2w, r2b, out);
}

// Round 2
// 1371.588 us; speedup vs baseline: 1.0309x; 1.0309x over previous
//
#include <hip/hip_runtime.h>

#define NN 50000
#define EE 800000
#define INF 32
#define PEF 15
#define HID 128
#define GG 64
#define NLAYERS 4

__device__ __forceinline__ float wave_allsum(float v) {
  #pragma unroll
  for (int off = 1; off < 64; off <<= 1) v += __shfl_xor(v, off);
  return v;
}

__device__ __forceinline__ float bflo(unsigned u) {
  return __builtin_bit_cast(float, u << 16);
}
__device__ __forceinline__ float bfhi(unsigned u) {
  return __builtin_bit_cast(float, u & 0xffff0000u);
}
__device__ __forceinline__ unsigned short f2bf(float v) {
  unsigned b = __builtin_bit_cast(unsigned, v);
  unsigned r = (b + 0x7fffu + ((b >> 16) & 1u)) >> 16;
  return (unsigned short)r;
}

// ---------------- weight packing ----------------
__global__ void pack_weights_kernel(const float* __restrict__ Wq, const float* __restrict__ Wk,
                                    const float* __restrict__ Wv, const float* __restrict__ Ws,
                                    const float* __restrict__ bq, const float* __restrict__ bk,
                                    const float* __restrict__ bv, const float* __restrict__ bs,
                                    float* __restrict__ Wcat, float* __restrict__ bcat) {
  int idx = blockIdx.x * blockDim.x + threadIdx.x;
  if (idx >= 512 * 128) return;
  int o = idx >> 7, j = idx & 127;
  int w = o >> 7, r = o & 127;
  const float* W = (w == 0) ? Wq : (w == 1) ? Wk : (w == 2) ? Wv : Ws;
  Wcat[idx] = W[r * 128 + j];
  if (j == 0) {
    const float* b = (w == 0) ? bq : (w == 1) ? bk : (w == 2) ? bv : bs;
    bcat[o] = b[r];
  }
}

__global__ void pack_nwt_kernel(const float* __restrict__ niw, float* __restrict__ nwT) {
  int idx = blockIdx.x * blockDim.x + threadIdx.x;
  if (idx >= 47 * 128) return;
  int j = idx >> 7, o = idx & 127;
  nwT[j * 128 + o] = niw[o * 47 + j];
}

// ---------------- node_in: h = [x|pe] @ W^T + b ----------------
__global__ __launch_bounds__(256) void nodein_kernel(const float* __restrict__ x,
    const float* __restrict__ pe, const float* __restrict__ nwT,
    const float* __restrict__ bias, float* __restrict__ h) {
  int wv = blockIdx.x * 4 + (threadIdx.x >> 6);
  if (wv >= NN) return;
  int lane = threadIdx.x & 63;
  float acc0 = bias[lane], acc1 = bias[64 + lane];
  const float* xr = x + (size_t)wv * INF;
  const float* pr = pe + (size_t)wv * PEF;
  #pragma unroll
  for (int j = 0; j < INF; j++) {
    float f = xr[j];
    acc0 += f * nwT[j * 128 + lane];
    acc1 += f * nwT[j * 128 + 64 + lane];
  }
  #pragma unroll
  for (int j = 0; j < PEF; j++) {
    float f = pr[j];
    acc0 += f * nwT[(INF + j) * 128 + lane];
    acc1 += f * nwT[(INF + j) * 128 + 64 + lane];
  }
  h[(size_t)wv * 128 + lane] = acc0;
  h[(size_t)wv * 128 + 64 + lane] = acc1;
}

// ---------------- CSR build ----------------
__global__ void count_kernel(const int* __restrict__ dst, int* __restrict__ counts) {
  int e = blockIdx.x * blockDim.x + threadIdx.x;
  if (e >= EE) return;
  atomicAdd(&counts[dst[e]], 1);
}

__global__ __launch_bounds__(1024) void scan_kernel(const int* __restrict__ counts,
    int* __restrict__ row_ptr, int* __restrict__ cursor) {
  __shared__ int wsum[16];
  __shared__ int carry_s;
  int t = threadIdx.x;
  int lane = t & 63, wid = t >> 6;
  if (t == 0) { carry_s = 0; row_ptr[0] = 0; }
  __syncthreads();
  for (int base = 0; base < NN; base += 1024) {
    int i = base + t;
    int v = (i < NN) ? counts[i] : 0;
    int xv = v;
    #pragma unroll
    for (int off = 1; off < 64; off <<= 1) {
      int u = __shfl_up(xv, off);
      if (lane >= off) xv += u;
    }
    if (lane == 63) wsum[wid] = xv;
    __syncthreads();
    if (wid == 0) {
      int w = (lane < 16) ? wsum[lane] : 0;
      #pragma unroll
      for (int off = 1; off < 16; off <<= 1) {
        int u = __shfl_up(w, off);
        if (lane >= off) w += u;
      }
      if (lane < 16) wsum[lane] = w;
    }
    __syncthreads();
    int offset = carry_s + (wid > 0 ? wsum[wid - 1] : 0);
    int incl = xv + offset;
    if (i < NN) { row_ptr[i + 1] = incl; cursor[i] = incl - v; }
    __syncthreads();
    if (t == 1023) carry_s = incl;
    __syncthreads();
  }
}

__global__ void scatter_kernel(const int* __restrict__ src, const int* __restrict__ dst,
                               int* __restrict__ cursor, int* __restrict__ srcs) {
  int e = blockIdx.x * blockDim.x + threadIdx.x;
  if (e >= EE) return;
  int d = dst[e];
  int p = atomicAdd(&cursor[d], 1);
  srcs[p] = src[e];
}

__global__ void gptr_kernel(const int* __restrict__ batch, int* __restrict__ gptr) {
  int g = threadIdx.x;
  if (g > GG) return;
  if (g == GG) { gptr[GG] = NN; return; }
  int lo = 0, hi = NN;
  while (lo < hi) {
    int mid = (lo + hi) >> 1;
    if (batch[mid] < g) lo = mid + 1; else hi = mid;
  }
  gptr[g] = lo;
}

// ---------------- GEMM: C[M,NO] = A[M,128] @ B[NO,128]^T + bias ----------------
// mode 0: NO=512, split write: cols 0-127 -> qbuf f32, 128-383 -> kvb bf16, 384-511 -> xrb f32
// mode 1: plain f32 out with relu into Cout (ldc)
__global__ __launch_bounds__(256) void gemm_bias_kernel(const float* __restrict__ A,
    const float* __restrict__ B, const float* __restrict__ bias,
    int M, int mode,
    float* __restrict__ qbuf, unsigned short* __restrict__ kvb, float* __restrict__ xrb,
    float* __restrict__ Cout, int ldc) {
  __shared__ float As[32][68];
  __shared__ float Bs[32][68];
  const int t = threadIdx.x;
  const int tx = t & 15, ty = t >> 4;
  const int m0 = blockIdx.x * 64, n0 = blockIdx.y * 64;
  const int lrow = t >> 2;
  const int lkc = (t & 3) * 8;
  float acc[4][4] = {};
  for (int k0 = 0; k0 < 128; k0 += 32) {
    float4 a0 = {0, 0, 0, 0}, a1 = {0, 0, 0, 0};
    int m = m0 + lrow;
    if (m < M) {
      const float4* ap = (const float4*)(A + (size_t)m * 128 + k0 + lkc);
      a0 = ap[0]; a1 = ap[1];
    }
    const float4* bp = (const float4*)(B + (size_t)(n0 + lrow) * 128 + k0 + lkc);
    float4 b0 = bp[0], b1 = bp[1];
    __syncthreads();
    As[lkc + 0][lrow] = a0.x; As[lkc + 1][lrow] = a0.y;
    As[lkc + 2][lrow] = a0.z; As[lkc + 3][lrow] = a0.w;
    As[lkc + 4][lrow] = a1.x; As[lkc + 5][lrow] = a1.y;
    As[lkc + 6][lrow] = a1.z; As[lkc + 7][lrow] = a1.w;
    Bs[lkc + 0][lrow] = b0.x; Bs[lkc + 1][lrow] = b0.y;
    Bs[lkc + 2][lrow] = b0.z; Bs[lkc + 3][lrow] = b0.w;
    Bs[lkc + 4][lrow] = b1.x; Bs[lkc + 5][lrow] = b1.y;
    Bs[lkc + 6][lrow] = b1.z; Bs[lkc + 7][lrow] = b1.w;
    __syncthreads();
    #pragma unroll
    for (int kk = 0; kk < 32; kk++) {
      float a[4], b[4];
      #pragma unroll
      for (int i = 0; i < 4; i++) a[i] = As[kk][ty * 4 + i];
      #pragma unroll
      for (int j = 0; j < 4; j++) b[j] = Bs[kk][tx * 4 + j];
      #pragma unroll
      for (int i = 0; i < 4; i++)
        #pragma unroll
        for (int j = 0; j < 4; j++) acc[i][j] += a[i] * b[j];
    }
  }
  const int grp = n0 >> 7;  // constant per block (n0 is 64-aligned, groups 128-wide)
  #pragma unroll
  for (int i = 0; i < 4; i++) {
    int m = m0 + ty * 4 + i;
    if (m >= M) continue;
    #pragma unroll
    for (int j = 0; j < 4; j++) {
      int n = n0 + tx * 4 + j;
      float v = acc[i][j] + bias[n];
      if (mode == 1) {
        Cout[(size_t)m * ldc + n] = fmaxf(v, 0.f);
      } else {
        if (grp == 0)      qbuf[(size_t)m * 128 + n] = v;
        else if (grp == 3) xrb[(size_t)m * 128 + (n - 384)] = v;
        else               kvb[(size_t)m * 256 + (n - 128)] = f2bf(v);
      }
    }
  }
}

// ---------------- edge attention (CSR, one wave per dst node, bf16 k/v) ----------------
__global__ __launch_bounds__(256) void attn_kernel(const float* __restrict__ qbuf,
    const unsigned* __restrict__ kvb,  // [N][128] uints = [N][256] bf16 (k|v)
    const int* __restrict__ row_ptr, const int* __restrict__ srcs,
    float* __restrict__ outb) {
  int wv = blockIdx.x * 4 + (threadIdx.x >> 6);
  if (wv >= NN) return;
  int lane = threadIdx.x & 63;
  const float2 q2 = ((const float2*)(qbuf + (size_t)wv * 128))[lane];
  int e0 = row_ptr[wv], e1 = row_ptr[wv + 1];
  const float scale = 0.17677669529663687f;  // 1/sqrt(32)
  float denom = 0.f, accx = 0.f, accy = 0.f;
  for (int base = e0; base < e1; base += 64) {
    int rem = e1 - base;
    int cnt = rem < 64 ? rem : 64;
    int mysrc = (lane < rem) ? srcs[base + lane] : 0;
    int i = 0;
    for (; i + 1 < cnt; i += 2) {
      int s0 = __shfl(mysrc, i);
      int s1 = __shfl(mysrc, i + 1);
      const unsigned* r0 = kvb + (size_t)s0 * 128;
      const unsigned* r1 = kvb + (size_t)s1 * 128;
      unsigned k0 = r0[lane], v0 = r0[64 + lane];
      unsigned k1 = r1[lane], v1 = r1[64 + lane];
      float p0 = q2.x * bflo(k0) + q2.y * bfhi(k0);
      float p1 = q2.x * bflo(k1) + q2.y * bfhi(k1);
      p0 += __shfl_xor(p0, 1); p1 += __shfl_xor(p1, 1);
      p0 += __shfl_xor(p0, 2); p1 += __shfl_xor(p1, 2);
      p0 += __shfl_xor(p0, 4); p1 += __shfl_xor(p1, 4);
      p0 += __shfl_xor(p0, 8); p1 += __shfl_xor(p1, 8);
      float ex0 = __expf(p0 * scale);
      float ex1 = __expf(p1 * scale);
      denom += ex0 + ex1;
      accx += ex0 * bflo(v0) + ex1 * bflo(v1);
      accy += ex0 * bfhi(v0) + ex1 * bfhi(v1);
    }
    if (i < cnt) {
      int s0 = __shfl(mysrc, i);
      const unsigned* r0 = kvb + (size_t)s0 * 128;
      unsigned k0 = r0[lane], v0 = r0[64 + lane];
      float p0 = q2.x * bflo(k0) + q2.y * bfhi(k0);
      p0 += __shfl_xor(p0, 1);
      p0 += __shfl_xor(p0, 2);
      p0 += __shfl_xor(p0, 4);
      p0 += __shfl_xor(p0, 8);
      float ex0 = __expf(p0 * scale);
      denom += ex0;
      accx += ex0 * bflo(v0);
      accy += ex0 * bfhi(v0);
    }
  }
  float inv = (e1 > e0) ? 1.0f / denom : 0.f;
  float2 o2;
  o2.x = accx * inv;
  o2.y = accy * inv;
  ((float2*)(outb + (size_t)wv * 128))[lane] = o2;
}

// ---------------- beta-gated residual + relu ----------------
__global__ __launch_bounds__(256) void beta_kernel(float* __restrict__ h,
    const float* __restrict__ xrb, const float* __restrict__ outb,
    const float* __restrict__ Wbeta) {
  int wv = blockIdx.x * 4 + (threadIdx.x >> 6);
  if (wv >= NN) return;
  int lane = threadIdx.x & 63;
  float2 o2 = ((const float2*)(outb + (size_t)wv * 128))[lane];
  float2 x2 = ((const float2*)(xrb + (size_t)wv * 128))[lane];
  const float2* wb = (const float2*)Wbeta;
  float2 wo = wb[lane], wx = wb[64 + lane], wd = wb[128 + lane];
  float part = o2.x * wo.x + o2.y * wo.y + x2.x * wx.x + x2.y * wx.y
             + (o2.x - x2.x) * wd.x + (o2.y - x2.y) * wd.y;
  part = wave_allsum(part);
  float beta = 1.f / (1.f + __expf(-part));
  float2* hp = (float2*)(h + (size_t)wv * 128);
  float2 h2 = hp[lane];
  float r0 = h2.x + beta * x2.x + (1.f - beta) * o2.x;
  float r1 = h2.y + beta * x2.y + (1.f - beta) * o2.y;
  h2.x = fmaxf(r0, 0.f);
  h2.y = fmaxf(r1, 0.f);
  hp[lane] = h2;
}

// ---------------- gate: gx = exp(relu(h@g1^T+b1) @ g2^T + b2); gden += gx ------
__global__ __launch_bounds__(256) void gate_kernel(const float* __restrict__ tb,
    const float* __restrict__ g2w, const float* __restrict__ g2b,
    const int* __restrict__ batch,
    float* __restrict__ gx, float* __restrict__ gden) {
  int wv = blockIdx.x * 4 + (threadIdx.x >> 6);
  if (wv >= NN) return;
  int lane = threadIdx.x & 63;
  float2 t2 = ((const float2*)(tb + (size_t)wv * 128))[lane];
  float2 w2 = ((const float2*)g2w)[lane];
  float p = t2.x * w2.x + t2.y * w2.y;
  p = wave_allsum(p);
  if (lane == 0) {
    float e = __expf(p + g2b[0]);
    gx[wv] = e;
    atomicAdd(&gden[batch[wv]], e);
  }
}

// ---------------- per-graph weighted aggregation (graph x chunk grid) ----------
__global__ __launch_bounds__(128) void gagg_kernel(const float* __restrict__ gx,
    const float* __restrict__ h, const int* __restrict__ gptr,
    float* __restrict__ gfeat_raw) {
  int g = blockIdx.x;
  int c = blockIdx.y;          // 0..31
  int d = threadIdx.x;
  int n0 = gptr[g], n1 = gptr[g + 1];
  float acc = 0.f;
  for (int n = n0 + c; n < n1; n += 32) acc += gx[n] * h[(size_t)n * 128 + d];
  atomicAdd(&gfeat_raw[g * 128 + d], acc);
}

// ---------------- readout ----------------
__global__ __launch_bounds__(128) void readout_kernel(const float* __restrict__ gfeat_raw,
    const float* __restrict__ gden,
    const float* __restrict__ r1w, const float* __restrict__ r1b,
    const float* __restrict__ r2w, const float* __restrict__ r2b,
    float* __restrict__ out) {
  int g = blockIdx.x;
  int u = threadIdx.x;
  __shared__ float sh[128];
  __shared__ float red[128];
  float dv = gden[g];
  float inv = (dv > 0.f) ? 1.f / dv : 0.f;
  sh[u] = gfeat_raw[g * 128 + u] * inv;
  __syncthreads();
  float tacc = r1b[u];
  for (int j = 0; j < 128; j++) tacc += sh[j] * r1w[u * 128 + j];
  tacc = fmaxf(tacc, 0.f);
  red[u] = tacc * r2w[u];
  __syncthreads();
  for (int off = 64; off > 0; off >>= 1) {
    if (u < off) red[u] += red[u + off];
    __syncthreads();
  }
  if (u == 0) out[g] = red[0] + r2b[0];
}

extern "C" void kernel_launch(void* const* d_in, const int* in_sizes, int n_in,
                              void* d_out, int out_size, void* d_ws, size_t ws_size,
                              hipStream_t stream) {
  (void)in_sizes; (void)n_in; (void)out_size; (void)ws_size;
  const float* x     = (const float*)d_in[0];
  const int*   ei    = (const int*)d_in[1];
  const int*   batch = (const int*)d_in[2];
  const float* pe    = (const float*)d_in[3];
  const float* niw   = (const float*)d_in[4];
  const float* nib   = (const float*)d_in[5];
  const float* Wq    = (const float*)d_in[6];
  const float* bq    = (const float*)d_in[7];
  const float* Wk    = (const float*)d_in[8];
  const float* bk    = (const float*)d_in[9];
  const float* Wv    = (const float*)d_in[10];
  const float* bv    = (const float*)d_in[11];
  const float* Wsk   = (const float*)d_in[12];
  const float* bsk   = (const float*)d_in[13];
  const float* Wbeta = (const float*)d_in[14];
  const float* g1w   = (const float*)d_in[15];
  const float* g1b   = (const float*)d_in[16];
  const float* g2w   = (const float*)d_in[17];
  const float* g2b   = (const float*)d_in[18];
  const float* r1w   = (const float*)d_in[19];
  const float* r1b   = (const float*)d_in[20];
  const float* r2w   = (const float*)d_in[21];
  const float* r2b   = (const float*)d_in[22];
  float* out = (float*)d_out;

  float* ws = (float*)d_ws;
  float* h     = ws; ws += (size_t)NN * 128;
  float* qbuf  = ws; ws += (size_t)NN * 128;
  float* xrb   = ws; ws += (size_t)NN * 128;
  float* outb  = ws; ws += (size_t)NN * 128;
  float* kvbf  = ws; ws += (size_t)NN * 128;  // bytes for [N][256] bf16
  float* Wcat  = ws; ws += 512 * 128;
  float* bcat  = ws; ws += 512;
  float* nwT   = ws; ws += 47 * 128;
  float* gx    = ws; ws += NN;
  float* gfeat = ws; ws += GG * 128;
  float* gden  = ws; ws += GG;
  int* row_ptr = (int*)ws;
  int* counts  = row_ptr + (NN + 1);
  int* cursor  = counts + NN;
  int* srcs    = cursor + NN;
  int* gptr    = srcs + EE;

  unsigned short* kvb = (unsigned short*)kvbf;
  const int* src = ei;
  const int* dst = ei + EE;

  hipMemsetAsync(counts, 0, NN * sizeof(int), stream);
  hipMemsetAsync(gfeat, 0, GG * 128 * sizeof(float), stream);
  hipMemsetAsync(gden, 0, GG * sizeof(float), stream);
  pack_weights_kernel<<<(512 * 128 + 255) / 256, 256, 0, stream>>>(
      Wq, Wk, Wv, Wsk, bq, bk, bv, bsk, Wcat, bcat);
  pack_nwt_kernel<<<(47 * 128 + 255) / 256, 256, 0, stream>>>(niw, nwT);
  nodein_kernel<<<12500, 256, 0, stream>>>(x, pe, nwT, nib, h);
  count_kernel<<<(EE + 255) / 256, 256, 0, stream>>>(dst, counts);
  scan_kernel<<<1, 1024, 0, stream>>>(counts, row_ptr, cursor);
  scatter_kernel<<<(EE + 255) / 256, 256, 0, stream>>>(src, dst, cursor, srcs);
  gptr_kernel<<<1, 128, 0, stream>>>(batch, gptr);

  for (int l = 0; l < NLAYERS; l++) {
    gemm_bias_kernel<<<dim3(782, 8), 256, 0, stream>>>(
        h, Wcat, bcat, NN, 0, qbuf, kvb, xrb, (float*)nullptr, 0);
    attn_kernel<<<12500, 256, 0, stream>>>(qbuf, (const unsigned*)kvb, row_ptr, srcs, outb);
    beta_kernel<<<12500, 256, 0, stream>>>(h, xrb, outb, Wbeta);
  }

  // gate hidden reuses qbuf
  gemm_bias_kernel<<<dim3(782, 2), 256, 0, stream>>>(
      h, g1w, g1b, NN, 1, (float*)nullptr, (unsigned short*)nullptr, (float*)nullptr, qbuf, 128);
  gate_kernel<<<12500, 256, 0, stream>>>(qbuf, g2w, g2b, batch, gx, gden);
  gagg_kernel<<<dim3(GG, 32), 128, 0, stream>>>(gx, h, gptr, gfeat);
  readout_kernel<<<GG, 128, 0, stream>>>(gfeat, gden, r1w, r1b, r2w, r2b, out);
}

// Round 3
// 799.659 us; speedup vs baseline: 1.7683x; 1.7152x over previous
//
#include <hip/hip_runtime.h>

#define NN 50000
#define EE 800000
#define INF 32
#define PEF 15
#define HID 128
#define GG 64
#define NLAYERS 4

typedef __bf16 bf16;
typedef __attribute__((ext_vector_type(8))) bf16 bf16x8;
typedef __attribute__((ext_vector_type(4))) float f32x4;

__device__ __forceinline__ float wave_allsum(float v) {
  #pragma unroll
  for (int off = 1; off < 64; off <<= 1) v += __shfl_xor(v, off);
  return v;
}

__device__ __forceinline__ float bflo(unsigned u) {
  return __builtin_bit_cast(float, u << 16);
}
__device__ __forceinline__ float bfhi(unsigned u) {
  return __builtin_bit_cast(float, u & 0xffff0000u);
}
__device__ __forceinline__ unsigned short f2bf(float v) {
  unsigned b = __builtin_bit_cast(unsigned, v);
  unsigned r = (b + 0x7fffu + ((b >> 16) & 1u)) >> 16;
  return (unsigned short)r;
}

// ---------------- weight packing ----------------
// Wcatb: bf16 [512][128] = rows q|k|v|skip ; bcat: f32 [512]
__global__ void pack_weights_kernel(const float* __restrict__ Wq, const float* __restrict__ Wk,
                                    const float* __restrict__ Wv, const float* __restrict__ Ws,
                                    const float* __restrict__ bq, const float* __restrict__ bk,
                                    const float* __restrict__ bv, const float* __restrict__ bs,
                                    unsigned short* __restrict__ Wcatb, float* __restrict__ bcat) {
  int idx = blockIdx.x * blockDim.x + threadIdx.x;
  if (idx >= 512 * 128) return;
  int o = idx >> 7, j = idx & 127;
  int w = o >> 7, r = o & 127;
  const float* W = (w == 0) ? Wq : (w == 1) ? Wk : (w == 2) ? Wv : Ws;
  Wcatb[idx] = f2bf(W[r * 128 + j]);
  if (j == 0) {
    const float* b = (w == 0) ? bq : (w == 1) ? bk : (w == 2) ? bv : bs;
    bcat[o] = b[r];
  }
}

__global__ void pack_nwt_kernel(const float* __restrict__ niw, float* __restrict__ nwT) {
  int idx = blockIdx.x * blockDim.x + threadIdx.x;
  if (idx >= 47 * 128) return;
  int j = idx >> 7, o = idx & 127;
  nwT[j * 128 + o] = niw[o * 47 + j];
}

__global__ void pack_g1_kernel(const float* __restrict__ g1w, unsigned short* __restrict__ g1wb) {
  int idx = blockIdx.x * blockDim.x + threadIdx.x;
  if (idx >= 128 * 128) return;
  g1wb[idx] = f2bf(g1w[idx]);
}

// ---------------- node_in: h = [x|pe] @ W^T + b (writes f32 h and bf16 hbf) ----
__global__ __launch_bounds__(256) void nodein_kernel(const float* __restrict__ x,
    const float* __restrict__ pe, const float* __restrict__ nwT,
    const float* __restrict__ bias, float* __restrict__ h,
    unsigned short* __restrict__ hbf) {
  int wv = blockIdx.x * 4 + (threadIdx.x >> 6);
  if (wv >= NN) return;
  int lane = threadIdx.x & 63;
  float acc0 = bias[lane], acc1 = bias[64 + lane];
  const float* xr = x + (size_t)wv * INF;
  const float* pr = pe + (size_t)wv * PEF;
  #pragma unroll
  for (int j = 0; j < INF; j++) {
    float f = xr[j];
    acc0 += f * nwT[j * 128 + lane];
    acc1 += f * nwT[j * 128 + 64 + lane];
  }
  #pragma unroll
  for (int j = 0; j < PEF; j++) {
    float f = pr[j];
    acc0 += f * nwT[(INF + j) * 128 + lane];
    acc1 += f * nwT[(INF + j) * 128 + 64 + lane];
  }
  h[(size_t)wv * 128 + lane] = acc0;
  h[(size_t)wv * 128 + 64 + lane] = acc1;
  hbf[(size_t)wv * 128 + lane] = f2bf(acc0);
  hbf[(size_t)wv * 128 + 64 + lane] = f2bf(acc1);
}

// ---------------- CSR build ----------------
__global__ void count_kernel(const int* __restrict__ dst, int* __restrict__ counts) {
  int e = blockIdx.x * blockDim.x + threadIdx.x;
  if (e >= EE) return;
  atomicAdd(&counts[dst[e]], 1);
}

__global__ __launch_bounds__(1024) void scan_kernel(const int* __restrict__ counts,
    int* __restrict__ row_ptr, int* __restrict__ cursor) {
  __shared__ int wsum[16];
  __shared__ int carry_s;
  int t = threadIdx.x;
  int lane = t & 63, wid = t >> 6;
  if (t == 0) { carry_s = 0; row_ptr[0] = 0; }
  __syncthreads();
  for (int base = 0; base < NN; base += 1024) {
    int i = base + t;
    int v = (i < NN) ? counts[i] : 0;
    int xv = v;
    #pragma unroll
    for (int off = 1; off < 64; off <<= 1) {
      int u = __shfl_up(xv, off);
      if (lane >= off) xv += u;
    }
    if (lane == 63) wsum[wid] = xv;
    __syncthreads();
    if (wid == 0) {
      int w = (lane < 16) ? wsum[lane] : 0;
      #pragma unroll
      for (int off = 1; off < 16; off <<= 1) {
        int u = __shfl_up(w, off);
        if (lane >= off) w += u;
      }
      if (lane < 16) wsum[lane] = w;
    }
    __syncthreads();
    int offset = carry_s + (wid > 0 ? wsum[wid - 1] : 0);
    int incl = xv + offset;
    if (i < NN) { row_ptr[i + 1] = incl; cursor[i] = incl - v; }
    __syncthreads();
    if (t == 1023) carry_s = incl;
    __syncthreads();
  }
}

__global__ void scatter_kernel(const int* __restrict__ src, const int* __restrict__ dst,
                               int* __restrict__ cursor, int* __restrict__ srcs) {
  int e = blockIdx.x * blockDim.x + threadIdx.x;
  if (e >= EE) return;
  int d = dst[e];
  int p = atomicAdd(&cursor[d], 1);
  srcs[p] = src[e];
}

__global__ void gptr_kernel(const int* __restrict__ batch, int* __restrict__ gptr) {
  int g = threadIdx.x;
  if (g > GG) return;
  if (g == GG) { gptr[GG] = NN; return; }
  int lo = 0, hi = NN;
  while (lo < hi) {
    int mid = (lo + hi) >> 1;
    if (batch[mid] < g) lo = mid + 1; else hi = mid;
  }
  gptr[g] = lo;
}

// ---------------- MFMA GEMM: C[M,NO] = A[M,128](bf16) @ B[NO,128](bf16)^T + bias
// mode 0 (NO=512): cols 0-127 -> qbuf f32, 128-383 -> kvb bf16, 384-511 -> xrb f32
// mode 1 (NO=128): relu, f32 -> Cout (ld 128)
// grid: (ceil(M/128), NO/64), block 256. Wave w: rows m0+w*32..+31, cols n0..n0+63.
__global__ __launch_bounds__(256) void gemm_mfma_kernel(
    const bf16* __restrict__ A, const bf16* __restrict__ B,
    const float* __restrict__ bias, int M, int mode,
    float* __restrict__ qbuf, unsigned short* __restrict__ kvb,
    float* __restrict__ xrb, float* __restrict__ Cout) {
  const int w = threadIdx.x >> 6, lane = threadIdx.x & 63;
  const int m0 = blockIdx.x * 128 + w * 32;
  const int n0 = blockIdx.y * 64;
  const int lrow = lane & 15, lk = (lane >> 4) * 8;
  int ma = m0 + lrow;      if (ma > M - 1) ma = M - 1;
  int mb = m0 + 16 + lrow; if (mb > M - 1) mb = M - 1;
  const bf16* a0p = A + (size_t)ma * 128 + lk;
  const bf16* a1p = A + (size_t)mb * 128 + lk;
  const bf16* bp  = B + (size_t)(n0 + lrow) * 128 + lk;
  f32x4 acc[2][4] = {};
  #pragma unroll
  for (int ks = 0; ks < 4; ks++) {
    bf16x8 a0 = *(const bf16x8*)(a0p + ks * 32);
    bf16x8 a1 = *(const bf16x8*)(a1p + ks * 32);
    #pragma unroll
    for (int nj = 0; nj < 4; nj++) {
      bf16x8 b = *(const bf16x8*)(bp + (size_t)nj * 16 * 128 + ks * 32);
      acc[0][nj] = __builtin_amdgcn_mfma_f32_16x16x32_bf16(a0, b, acc[0][nj], 0, 0, 0);
      acc[1][nj] = __builtin_amdgcn_mfma_f32_16x16x32_bf16(a1, b, acc[1][nj], 0, 0, 0);
    }
  }
  const int rbase = (lane >> 4) * 4;
  const int grp = n0 >> 7;
  #pragma unroll
  for (int mi = 0; mi < 2; mi++) {
    #pragma unroll
    for (int r = 0; r < 4; r++) {
      int m = m0 + mi * 16 + rbase + r;
      if (m >= M) continue;
      #pragma unroll
      for (int nj = 0; nj < 4; nj++) {
        int n = n0 + nj * 16 + lrow;
        float v = acc[mi][nj][r] + bias[n];
        if (mode == 1) {
          Cout[(size_t)m * 128 + n] = fmaxf(v, 0.f);
        } else {
          if (grp == 0)      qbuf[(size_t)m * 128 + n] = v;
          else if (grp == 3) xrb[(size_t)m * 128 + (n - 384)] = v;
          else               kvb[(size_t)m * 256 + (n - 128)] = f2bf(v);
        }
      }
    }
  }
}

// ---------------- edge attention (CSR, one wave per dst node, bf16 k/v) --------
__global__ __launch_bounds__(256) void attn_kernel(const float* __restrict__ qbuf,
    const unsigned* __restrict__ kvb,  // [N][128] uints = [N][256] bf16 (k|v)
    const int* __restrict__ row_ptr, const int* __restrict__ srcs,
    float* __restrict__ outb) {
  int wv = blockIdx.x * 4 + (threadIdx.x >> 6);
  if (wv >= NN) return;
  int lane = threadIdx.x & 63;
  const float2 q2 = ((const float2*)(qbuf + (size_t)wv * 128))[lane];
  int e0 = row_ptr[wv], e1 = row_ptr[wv + 1];
  const float scale = 0.17677669529663687f;  // 1/sqrt(32)
  float denom = 0.f, accx = 0.f, accy = 0.f;
  for (int base = e0; base < e1; base += 64) {
    int rem = e1 - base;
    int cnt = rem < 64 ? rem : 64;
    int mysrc = (lane < rem) ? srcs[base + lane] : 0;
    int i = 0;
    for (; i + 1 < cnt; i += 2) {
      int s0 = __shfl(mysrc, i);
      int s1 = __shfl(mysrc, i + 1);
      const unsigned* r0 = kvb + (size_t)s0 * 128;
      const unsigned* r1 = kvb + (size_t)s1 * 128;
      unsigned k0 = r0[lane], v0 = r0[64 + lane];
      unsigned k1 = r1[lane], v1 = r1[64 + lane];
      float p0 = q2.x * bflo(k0) + q2.y * bfhi(k0);
      float p1 = q2.x * bflo(k1) + q2.y * bfhi(k1);
      p0 += __shfl_xor(p0, 1); p1 += __shfl_xor(p1, 1);
      p0 += __shfl_xor(p0, 2); p1 += __shfl_xor(p1, 2);
      p0 += __shfl_xor(p0, 4); p1 += __shfl_xor(p1, 4);
      p0 += __shfl_xor(p0, 8); p1 += __shfl_xor(p1, 8);
      float ex0 = __expf(p0 * scale);
      float ex1 = __expf(p1 * scale);
      denom += ex0 + ex1;
      accx += ex0 * bflo(v0) + ex1 * bflo(v1);
      accy += ex0 * bfhi(v0) + ex1 * bfhi(v1);
    }
    if (i < cnt) {
      int s0 = __shfl(mysrc, i);
      const unsigned* r0 = kvb + (size_t)s0 * 128;
      unsigned k0 = r0[lane], v0 = r0[64 + lane];
      float p0 = q2.x * bflo(k0) + q2.y * bfhi(k0);
      p0 += __shfl_xor(p0, 1);
      p0 += __shfl_xor(p0, 2);
      p0 += __shfl_xor(p0, 4);
      p0 += __shfl_xor(p0, 8);
      float ex0 = __expf(p0 * scale);
      denom += ex0;
      accx += ex0 * bflo(v0);
      accy += ex0 * bfhi(v0);
    }
  }
  float inv = (e1 > e0) ? 1.0f / denom : 0.f;
  float2 o2;
  o2.x = accx * inv;
  o2.y = accy * inv;
  ((float2*)(outb + (size_t)wv * 128))[lane] = o2;
}

// ---------------- beta-gated residual + relu (updates h f32 + hbf bf16) --------
__global__ __launch_bounds__(256) void beta_kernel(float* __restrict__ h,
    unsigned short* __restrict__ hbf,
    const float* __restrict__ xrb, const float* __restrict__ outb,
    const float* __restrict__ Wbeta) {
  int wv = blockIdx.x * 4 + (threadIdx.x >> 6);
  if (wv >= NN) return;
  int lane = threadIdx.x & 63;
  float2 o2 = ((const float2*)(outb + (size_t)wv * 128))[lane];
  float2 x2 = ((const float2*)(xrb + (size_t)wv * 128))[lane];
  const float2* wb = (const float2*)Wbeta;
  float2 wo = wb[lane], wx = wb[64 + lane], wd = wb[128 + lane];
  float part = o2.x * wo.x + o2.y * wo.y + x2.x * wx.x + x2.y * wx.y
             + (o2.x - x2.x) * wd.x + (o2.y - x2.y) * wd.y;
  part = wave_allsum(part);
  float beta = 1.f / (1.f + __expf(-part));
  float2* hp = (float2*)(h + (size_t)wv * 128);
  float2 h2 = hp[lane];
  float r0 = fmaxf(h2.x + beta * x2.x + (1.f - beta) * o2.x, 0.f);
  float r1 = fmaxf(h2.y + beta * x2.y + (1.f - beta) * o2.y, 0.f);
  h2.x = r0; h2.y = r1;
  hp[lane] = h2;
  unsigned short* hb = hbf + (size_t)wv * 128 + 2 * lane;
  hb[0] = f2bf(r0);
  hb[1] = f2bf(r1);
}

// ---------------- gate: gx = exp(relu(h@g1^T+b1) @ g2^T + b2) ------------------
__global__ __launch_bounds__(256) void gate_kernel(const float* __restrict__ tb,
    const float* __restrict__ g2w, const float* __restrict__ g2b,
    float* __restrict__ gx) {
  int wv = blockIdx.x * 4 + (threadIdx.x >> 6);
  if (wv >= NN) return;
  int lane = threadIdx.x & 63;
  float2 t2 = ((const float2*)(tb + (size_t)wv * 128))[lane];
  float2 w2 = ((const float2*)g2w)[lane];
  float p = t2.x * w2.x + t2.y * w2.y;
  p = wave_allsum(p);
  if (lane == 0) gx[wv] = __expf(p + g2b[0]);
}

// ---------------- per-graph gate-denominator (no atomics) ----------------------
__global__ __launch_bounds__(256) void gden_kernel(const float* __restrict__ gx,
    const int* __restrict__ gptr, float* __restrict__ gden) {
  int g = blockIdx.x, t = threadIdx.x;
  int n0 = gptr[g], n1 = gptr[g + 1];
  float s = 0.f;
  for (int n = n0 + t; n < n1; n += 256) s += gx[n];
  s = wave_allsum(s);
  __shared__ float red[4];
  if ((t & 63) == 0) red[t >> 6] = s;
  __syncthreads();
  if (t == 0) gden[g] = red[0] + red[1] + red[2] + red[3];
}

// ---------------- per-graph weighted aggregation (graph x chunk grid) ----------
__global__ __launch_bounds__(128) void gagg_kernel(const float* __restrict__ gx,
    const float* __restrict__ h, const int* __restrict__ gptr,
    float* __restrict__ gfeat_raw) {
  int g = blockIdx.x;
  int c = blockIdx.y;
  int d = threadIdx.x;
  int n0 = gptr[g], n1 = gptr[g + 1];
  float acc = 0.f;
  for (int n = n0 + c; n < n1; n += 32) acc += gx[n] * h[(size_t)n * 128 + d];
  atomicAdd(&gfeat_raw[g * 128 + d], acc);
}

// ---------------- readout ----------------
__global__ __launch_bounds__(128) void readout_kernel(const float* __restrict__ gfeat_raw,
    const float* __restrict__ gden,
    const float* __restrict__ r1w, const float* __restrict__ r1b,
    const float* __restrict__ r2w, const float* __restrict__ r2b,
    float* __restrict__ out) {
  int g = blockIdx.x;
  int u = threadIdx.x;
  __shared__ float sh[128];
  __shared__ float red[128];
  float dv = gden[g];
  float inv = (dv > 0.f) ? 1.f / dv : 0.f;
  sh[u] = gfeat_raw[g * 128 + u] * inv;
  __syncthreads();
  float tacc = r1b[u];
  for (int j = 0; j < 128; j++) tacc += sh[j] * r1w[u * 128 + j];
  tacc = fmaxf(tacc, 0.f);
  red[u] = tacc * r2w[u];
  __syncthreads();
  for (int off = 64; off > 0; off >>= 1) {
    if (u < off) red[u] += red[u + off];
    __syncthreads();
  }
  if (u == 0) out[g] = red[0] + r2b[0];
}

extern "C" void kernel_launch(void* const* d_in, const int* in_sizes, int n_in,
                              void* d_out, int out_size, void* d_ws, size_t ws_size,
                              hipStream_t stream) {
  (void)in_sizes; (void)n_in; (void)out_size; (void)ws_size;
  const float* x     = (const float*)d_in[0];
  const int*   ei    = (const int*)d_in[1];
  const int*   batch = (const int*)d_in[2];
  const float* pe    = (const float*)d_in[3];
  const float* niw   = (const float*)d_in[4];
  const float* nib   = (const float*)d_in[5];
  const float* Wq    = (const float*)d_in[6];
  const float* bq    = (const float*)d_in[7];
  const float* Wk    = (const float*)d_in[8];
  const float* bk    = (const float*)d_in[9];
  const float* Wv    = (const float*)d_in[10];
  const float* bv    = (const float*)d_in[11];
  const float* Wsk   = (const float*)d_in[12];
  const float* bsk   = (const float*)d_in[13];
  const float* Wbeta = (const float*)d_in[14];
  const float* g1w   = (const float*)d_in[15];
  const float* g1b   = (const float*)d_in[16];
  const float* g2w   = (const float*)d_in[17];
  const float* g2b   = (const float*)d_in[18];
  const float* r1w   = (const float*)d_in[19];
  const float* r1b   = (const float*)d_in[20];
  const float* r2w   = (const float*)d_in[21];
  const float* r2b   = (const float*)d_in[22];
  float* out = (float*)d_out;

  float* ws = (float*)d_ws;
  float* h     = ws; ws += (size_t)NN * 128;
  float* qbuf  = ws; ws += (size_t)NN * 128;
  float* xrb   = ws; ws += (size_t)NN * 128;
  float* outb  = ws; ws += (size_t)NN * 128;
  float* kvbf  = ws; ws += (size_t)NN * 128;  // [N][256] bf16
  float* hbff  = ws; ws += (size_t)NN * 64;   // [N][128] bf16
  float* Wcatf = ws; ws += 512 * 64;          // [512][128] bf16
  float* g1wbf = ws; ws += 128 * 64;          // [128][128] bf16
  float* bcat  = ws; ws += 512;
  float* nwT   = ws; ws += 47 * 128;
  float* gx    = ws; ws += NN;
  float* gfeat = ws; ws += GG * 128;
  float* gden  = ws; ws += GG;
  int* row_ptr = (int*)ws;
  int* counts  = row_ptr + (NN + 1);
  int* cursor  = counts + NN;
  int* srcs    = cursor + NN;
  int* gptr    = srcs + EE;

  unsigned short* kvb   = (unsigned short*)kvbf;
  unsigned short* hbf   = (unsigned short*)hbff;
  unsigned short* Wcatb = (unsigned short*)Wcatf;
  unsigned short* g1wb  = (unsigned short*)g1wbf;
  const int* src = ei;
  const int* dst = ei + EE;

  hipMemsetAsync(counts, 0, NN * sizeof(int), stream);
  hipMemsetAsync(gfeat, 0, GG * 128 * sizeof(float), stream);
  pack_weights_kernel<<<(512 * 128 + 255) / 256, 256, 0, stream>>>(
      Wq, Wk, Wv, Wsk, bq, bk, bv, bsk, Wcatb, bcat);
  pack_nwt_kernel<<<(47 * 128 + 255) / 256, 256, 0, stream>>>(niw, nwT);
  pack_g1_kernel<<<(128 * 128 + 255) / 256, 256, 0, stream>>>(g1w, g1wb);
  nodein_kernel<<<12500, 256, 0, stream>>>(x, pe, nwT, nib, h, hbf);
  count_kernel<<<(EE + 255) / 256, 256, 0, stream>>>(dst, counts);
  scan_kernel<<<1, 1024, 0, stream>>>(counts, row_ptr, cursor);
  scatter_kernel<<<(EE + 255) / 256, 256, 0, stream>>>(src, dst, cursor, srcs);
  gptr_kernel<<<1, 128, 0, stream>>>(batch, gptr);

  const int MB = (NN + 127) / 128;  // 391
  for (int l = 0; l < NLAYERS; l++) {
    gemm_mfma_kernel<<<dim3(MB, 8), 256, 0, stream>>>(
        (const bf16*)hbf, (const bf16*)Wcatb, bcat, NN, 0,
        qbuf, kvb, xrb, (float*)nullptr);
    attn_kernel<<<12500, 256, 0, stream>>>(qbuf, (const unsigned*)kvb, row_ptr, srcs, outb);
    beta_kernel<<<12500, 256, 0, stream>>>(h, hbf, xrb, outb, Wbeta);
  }

  gemm_mfma_kernel<<<dim3(MB, 2), 256, 0, stream>>>(
      (const bf16*)hbf, (const bf16*)g1wb, g1b, NN, 1,
      (float*)nullptr, (unsigned short*)nullptr, (float*)nullptr, qbuf);
  gate_kernel<<<12500, 256, 0, stream>>>(qbuf, g2w, g2b, gx);
  gden_kernel<<<GG, 256, 0, stream>>>(gx, gptr, gden);
  gagg_kernel<<<dim3(GG, 32), 128, 0, stream>>>(gx, h, gptr, gfeat);
  readout_kernel<<<GG, 128, 0, stream>>>(gfeat, gden, r1w, r1b, r2w, r2b, out);
}

// Round 4
// 683.192 us; speedup vs baseline: 2.0697x; 1.1705x over previous
//
#include <hip/hip_runtime.h>

#define NN 50000
#define EE 800000
#define INF 32
#define PEF 15
#define HID 128
#define GG 64
#define NLAYERS 4
#define NBLK 196  // ceil(NN/256)

typedef __bf16 bf16;
typedef __attribute__((ext_vector_type(8))) bf16 bf16x8;
typedef __attribute__((ext_vector_type(4))) float f32x4;
typedef __attribute__((ext_vector_type(2))) float f32x2;

__device__ __forceinline__ float wave_allsum(float v) {
  #pragma unroll
  for (int off = 1; off < 64; off <<= 1) v += __shfl_xor(v, off);
  return v;
}

__device__ __forceinline__ float bflo(unsigned u) {
  return __builtin_bit_cast(float, u << 16);
}
__device__ __forceinline__ float bfhi(unsigned u) {
  return __builtin_bit_cast(float, u & 0xffff0000u);
}
__device__ __forceinline__ unsigned short f2bf(float v) {
  unsigned b = __builtin_bit_cast(unsigned, v);
  unsigned r = (b + 0x7fffu + ((b >> 16) & 1u)) >> 16;
  return (unsigned short)r;
}
__device__ __forceinline__ unsigned char f2fp8(float v) {
  int p = __builtin_amdgcn_cvt_pk_fp8_f32(v, v, 0, false);
  return (unsigned char)(p & 0xff);
}

// ---------------- weight packing ----------------
__global__ void pack_weights_kernel(const float* __restrict__ Wq, const float* __restrict__ Wk,
                                    const float* __restrict__ Wv, const float* __restrict__ Ws,
                                    const float* __restrict__ bq, const float* __restrict__ bk,
                                    const float* __restrict__ bv, const float* __restrict__ bs,
                                    unsigned short* __restrict__ Wcatb, float* __restrict__ bcat) {
  int idx = blockIdx.x * blockDim.x + threadIdx.x;
  if (idx >= 512 * 128) return;
  int o = idx >> 7, j = idx & 127;
  int w = o >> 7, r = o & 127;
  const float* W = (w == 0) ? Wq : (w == 1) ? Wk : (w == 2) ? Wv : Ws;
  Wcatb[idx] = f2bf(W[r * 128 + j]);
  if (j == 0) {
    const float* b = (w == 0) ? bq : (w == 1) ? bk : (w == 2) ? bv : bs;
    bcat[o] = b[r];
  }
}

__global__ void pack_nwt_kernel(const float* __restrict__ niw, float* __restrict__ nwT) {
  int idx = blockIdx.x * blockDim.x + threadIdx.x;
  if (idx >= 47 * 128) return;
  int j = idx >> 7, o = idx & 127;
  nwT[j * 128 + o] = niw[o * 47 + j];
}

__global__ void pack_g1_kernel(const float* __restrict__ g1w, unsigned short* __restrict__ g1wb) {
  int idx = blockIdx.x * blockDim.x + threadIdx.x;
  if (idx >= 128 * 128) return;
  g1wb[idx] = f2bf(g1w[idx]);
}

// ---------------- node_in ----------------
__global__ __launch_bounds__(256) void nodein_kernel(const float* __restrict__ x,
    const float* __restrict__ pe, const float* __restrict__ nwT,
    const float* __restrict__ bias, float* __restrict__ h,
    unsigned short* __restrict__ hbf) {
  int wv = blockIdx.x * 4 + (threadIdx.x >> 6);
  if (wv >= NN) return;
  int lane = threadIdx.x & 63;
  float acc0 = bias[lane], acc1 = bias[64 + lane];
  const float* xr = x + (size_t)wv * INF;
  const float* pr = pe + (size_t)wv * PEF;
  #pragma unroll
  for (int j = 0; j < INF; j++) {
    float f = xr[j];
    acc0 += f * nwT[j * 128 + lane];
    acc1 += f * nwT[j * 128 + 64 + lane];
  }
  #pragma unroll
  for (int j = 0; j < PEF; j++) {
    float f = pr[j];
    acc0 += f * nwT[(INF + j) * 128 + lane];
    acc1 += f * nwT[(INF + j) * 128 + 64 + lane];
  }
  h[(size_t)wv * 128 + lane] = acc0;
  h[(size_t)wv * 128 + 64 + lane] = acc1;
  hbf[(size_t)wv * 128 + lane] = f2bf(acc0);
  hbf[(size_t)wv * 128 + 64 + lane] = f2bf(acc1);
}

// ---------------- CSR build ----------------
__global__ void count_kernel(const int* __restrict__ dst, int* __restrict__ counts) {
  int e = blockIdx.x * blockDim.x + threadIdx.x;
  if (e >= EE) return;
  atomicAdd(&counts[dst[e]], 1);
}

__global__ __launch_bounds__(256) void bsum_kernel(const int* __restrict__ counts,
                                                   int* __restrict__ bsum) {
  int b = blockIdx.x, t = threadIdx.x;
  int i = b * 256 + t;
  int v = (i < NN) ? counts[i] : 0;
  #pragma unroll
  for (int off = 1; off < 64; off <<= 1) v += __shfl_xor(v, off);
  __shared__ int red[4];
  if ((t & 63) == 0) red[t >> 6] = v;
  __syncthreads();
  if (t == 0) bsum[b] = red[0] + red[1] + red[2] + red[3];
}

__global__ void bscan_kernel(const int* __restrict__ bsum, int* __restrict__ bbase) {
  int lane = threadIdx.x;  // 64 threads, 1 block
  int carry = 0;
  for (int c = 0; c < NBLK; c += 64) {
    int i = c + lane;
    int v = (i < NBLK) ? bsum[i] : 0;
    int x = v;
    #pragma unroll
    for (int off = 1; off < 64; off <<= 1) {
      int u = __shfl_up(x, off);
      if (lane >= off) x += u;
    }
    if (i < NBLK) bbase[i] = carry + x - v;
    carry += __shfl(x, 63);
  }
}

__global__ __launch_bounds__(256) void rowptr_kernel(const int* __restrict__ counts,
    const int* __restrict__ bbase, int* __restrict__ row_ptr, int* __restrict__ cursor) {
  int b = blockIdx.x, t = threadIdx.x;
  int lane = t & 63, wid = t >> 6;
  int i = b * 256 + t;
  int v = (i < NN) ? counts[i] : 0;
  int x = v;
  #pragma unroll
  for (int off = 1; off < 64; off <<= 1) {
    int u = __shfl_up(x, off);
    if (lane >= off) x += u;
  }
  __shared__ int wsum[4];
  if (lane == 63) wsum[wid] = x;
  __syncthreads();
  int offs = bbase[b];
  for (int k = 0; k < wid; k++) offs += wsum[k];
  int incl = offs + x;
  if (i < NN) { row_ptr[i + 1] = incl; cursor[i] = incl - v; }
  if (b == 0 && t == 0) row_ptr[0] = 0;
}

__global__ void scatter_kernel(const int* __restrict__ src, const int* __restrict__ dst,
                               int* __restrict__ cursor, int* __restrict__ srcs) {
  int e = blockIdx.x * blockDim.x + threadIdx.x;
  if (e >= EE) return;
  int d = dst[e];
  int p = atomicAdd(&cursor[d], 1);
  srcs[p] = src[e];
}

__global__ void gptr_kernel(const int* __restrict__ batch, int* __restrict__ gptr) {
  int g = threadIdx.x;
  if (g > GG) return;
  if (g == GG) { gptr[GG] = NN; return; }
  int lo = 0, hi = NN;
  while (lo < hi) {
    int mid = (lo + hi) >> 1;
    if (batch[mid] < g) lo = mid + 1; else hi = mid;
  }
  gptr[g] = lo;
}

// ---------------- MFMA GEMM ----------------
// mode 0 (NO=512): cols 0-127 -> qbb bf16, 128-255 -> k fp8, 256-383 -> v bf16, 384-511 -> xrb f32
// mode 1 (NO=128): relu, f32 -> Cout (ld 128)
__global__ __launch_bounds__(256) void gemm_mfma_kernel(
    const bf16* __restrict__ A, const bf16* __restrict__ B,
    const float* __restrict__ bias, int M, int mode,
    unsigned short* __restrict__ qbb, unsigned char* __restrict__ kvb,
    float* __restrict__ xrb, float* __restrict__ Cout) {
  const int w = threadIdx.x >> 6, lane = threadIdx.x & 63;
  const int m0 = blockIdx.x * 128 + w * 32;
  const int n0 = blockIdx.y * 64;
  const int lrow = lane & 15, lk = (lane >> 4) * 8;
  int ma = m0 + lrow;      if (ma > M - 1) ma = M - 1;
  int mb = m0 + 16 + lrow; if (mb > M - 1) mb = M - 1;
  const bf16* a0p = A + (size_t)ma * 128 + lk;
  const bf16* a1p = A + (size_t)mb * 128 + lk;
  const bf16* bp  = B + (size_t)(n0 + lrow) * 128 + lk;
  f32x4 acc[2][4] = {};
  #pragma unroll
  for (int ks = 0; ks < 4; ks++) {
    bf16x8 a0 = *(const bf16x8*)(a0p + ks * 32);
    bf16x8 a1 = *(const bf16x8*)(a1p + ks * 32);
    #pragma unroll
    for (int nj = 0; nj < 4; nj++) {
      bf16x8 b = *(const bf16x8*)(bp + (size_t)nj * 16 * 128 + ks * 32);
      acc[0][nj] = __builtin_amdgcn_mfma_f32_16x16x32_bf16(a0, b, acc[0][nj], 0, 0, 0);
      acc[1][nj] = __builtin_amdgcn_mfma_f32_16x16x32_bf16(a1, b, acc[1][nj], 0, 0, 0);
    }
  }
  const int rbase = (lane >> 4) * 4;
  const int grp = n0 >> 7;
  #pragma unroll
  for (int mi = 0; mi < 2; mi++) {
    #pragma unroll
    for (int r = 0; r < 4; r++) {
      int m = m0 + mi * 16 + rbase + r;
      if (m >= M) continue;
      #pragma unroll
      for (int nj = 0; nj < 4; nj++) {
        int n = n0 + nj * 16 + lrow;
        float v = acc[mi][nj][r] + bias[n];
        if (mode == 1) {
          Cout[(size_t)m * 128 + n] = fmaxf(v, 0.f);
        } else {
          if (grp == 0)      qbb[(size_t)m * 128 + n] = f2bf(v);
          else if (grp == 1) kvb[(size_t)m * 384 + (n - 128)] = f2fp8(v);
          else if (grp == 2) *(unsigned short*)(kvb + (size_t)m * 384 + 128 + (size_t)(n - 256) * 2) = f2bf(v);
          else               xrb[(size_t)m * 128 + (n - 384)] = v;
        }
      }
    }
  }
}

// ---------------- fused edge attention + beta residual ----------------
__global__ __launch_bounds__(256) void attn_beta_kernel(
    const unsigned* __restrict__ qb,        // [N][64] uint = [N][128] bf16
    const unsigned char* __restrict__ kvb,  // [N][384] B: k fp8[128] | v bf16[256B]
    const int* __restrict__ row_ptr, const int* __restrict__ srcs,
    const float* __restrict__ xrb, const float* __restrict__ Wbeta,
    float* __restrict__ h, unsigned* __restrict__ hbf4) {
  int wv = blockIdx.x * 4 + (threadIdx.x >> 6);
  if (wv >= NN) return;
  int lane = threadIdx.x & 63;
  unsigned qu = qb[(size_t)wv * 64 + lane];
  float qx = bflo(qu), qy = bfhi(qu);
  int e0 = row_ptr[wv], e1 = row_ptr[wv + 1];
  const float C = 0.25503486f;  // (1/sqrt(32)) * log2(e)
  const bool odd = lane & 1;
  float denom = 0.f, accx = 0.f, accy = 0.f;
  for (int base = e0; base < e1; base += 64) {
    int rem = e1 - base;
    int cnt = rem < 64 ? rem : 64;
    int mysrc = (lane < rem) ? srcs[base + lane] : 0;
    int i = 0;
    for (; i + 1 < cnt; i += 2) {
      int s0 = __shfl(mysrc, i);
      int s1 = __shfl(mysrc, i + 1);
      const unsigned char* r0 = kvb + (size_t)s0 * 384;
      const unsigned char* r1 = kvb + (size_t)s1 * 384;
      unsigned short ku0 = *(const unsigned short*)(r0 + 2 * lane);
      unsigned short ku1 = *(const unsigned short*)(r1 + 2 * lane);
      unsigned vu0 = *(const unsigned*)(r0 + 128 + 4 * lane);
      unsigned vu1 = *(const unsigned*)(r1 + 128 + 4 * lane);
      f32x2 kd0 = __builtin_amdgcn_cvt_pk_f32_fp8((int)ku0, false);
      f32x2 kd1 = __builtin_amdgcn_cvt_pk_f32_fp8((int)ku1, false);
      float p0 = qx * kd0.x + qy * kd0.y;
      float p1 = qx * kd1.x + qy * kd1.y;
      float z = odd ? p1 : p0;
      float ww = odd ? p0 : p1;
      z += __shfl_xor(ww, 1);
      z += __shfl_xor(z, 2);
      z += __shfl_xor(z, 4);
      z += __shfl_xor(z, 8);
      float ex = exp2f(z * C);
      float exo = __shfl_xor(ex, 1);
      float ex0 = odd ? exo : ex;
      float ex1 = odd ? ex : exo;
      denom += ex0 + ex1;
      accx += ex0 * bflo(vu0) + ex1 * bflo(vu1);
      accy += ex0 * bfhi(vu0) + ex1 * bfhi(vu1);
    }
    if (i < cnt) {
      int s0 = __shfl(mysrc, i);
      const unsigned char* r0 = kvb + (size_t)s0 * 384;
      unsigned short ku0 = *(const unsigned short*)(r0 + 2 * lane);
      unsigned vu0 = *(const unsigned*)(r0 + 128 + 4 * lane);
      f32x2 kd0 = __builtin_amdgcn_cvt_pk_f32_fp8((int)ku0, false);
      float p0 = qx * kd0.x + qy * kd0.y;
      p0 += __shfl_xor(p0, 1);
      p0 += __shfl_xor(p0, 2);
      p0 += __shfl_xor(p0, 4);
      p0 += __shfl_xor(p0, 8);
      float ex0 = exp2f(p0 * C);
      denom += ex0;
      accx += ex0 * bflo(vu0);
      accy += ex0 * bfhi(vu0);
    }
  }
  float inv = (e1 > e0) ? 1.0f / denom : 0.f;
  float ox = accx * inv, oy = accy * inv;
  // ---- beta gate + residual + relu ----
  float2 x2 = ((const float2*)(xrb + (size_t)wv * 128))[lane];
  const float2* wb = (const float2*)Wbeta;
  float2 wo = wb[lane], wx = wb[64 + lane], wd = wb[128 + lane];
  float part = ox * wo.x + oy * wo.y + x2.x * wx.x + x2.y * wx.y
             + (ox - x2.x) * wd.x + (oy - x2.y) * wd.y;
  part = wave_allsum(part);
  float beta = 1.f / (1.f + __expf(-part));
  float2* hp = (float2*)(h + (size_t)wv * 128);
  float2 h2 = hp[lane];
  float r0 = fmaxf(h2.x + beta * x2.x + (1.f - beta) * ox, 0.f);
  float r1 = fmaxf(h2.y + beta * x2.y + (1.f - beta) * oy, 0.f);
  h2.x = r0; h2.y = r1;
  hp[lane] = h2;
  hbf4[(size_t)wv * 64 + lane] = (unsigned)f2bf(r0) | ((unsigned)f2bf(r1) << 16);
}

// ---------------- gate ----------------
__global__ __launch_bounds__(256) void gate_kernel(const float* __restrict__ tb,
    const float* __restrict__ g2w, const float* __restrict__ g2b,
    float* __restrict__ gx) {
  int wv = blockIdx.x * 4 + (threadIdx.x >> 6);
  if (wv >= NN) return;
  int lane = threadIdx.x & 63;
  float2 t2 = ((const float2*)(tb + (size_t)wv * 128))[lane];
  float2 w2 = ((const float2*)g2w)[lane];
  float p = t2.x * w2.x + t2.y * w2.y;
  p = wave_allsum(p);
  if (lane == 0) gx[wv] = __expf(p + g2b[0]);
}

__global__ __launch_bounds__(256) void gden_kernel(const float* __restrict__ gx,
    const int* __restrict__ gptr, float* __restrict__ gden) {
  int g = blockIdx.x, t = threadIdx.x;
  int n0 = gptr[g], n1 = gptr[g + 1];
  float s = 0.f;
  for (int n = n0 + t; n < n1; n += 256) s += gx[n];
  s = wave_allsum(s);
  __shared__ float red[4];
  if ((t & 63) == 0) red[t >> 6] = s;
  __syncthreads();
  if (t == 0) gden[g] = red[0] + red[1] + red[2] + red[3];
}

__global__ __launch_bounds__(128) void gagg_kernel(const float* __restrict__ gx,
    const float* __restrict__ h, const int* __restrict__ gptr,
    float* __restrict__ gfeat_raw) {
  int g = blockIdx.x;
  int c = blockIdx.y;
  int d = threadIdx.x;
  int n0 = gptr[g], n1 = gptr[g + 1];
  float acc = 0.f;
  for (int n = n0 + c; n < n1; n += 32) acc += gx[n] * h[(size_t)n * 128 + d];
  atomicAdd(&gfeat_raw[g * 128 + d], acc);
}

__global__ __launch_bounds__(128) void readout_kernel(const float* __restrict__ gfeat_raw,
    const float* __restrict__ gden,
    const float* __restrict__ r1w, const float* __restrict__ r1b,
    const float* __restrict__ r2w, const float* __restrict__ r2b,
    float* __restrict__ out) {
  int g = blockIdx.x;
  int u = threadIdx.x;
  __shared__ float sh[128];
  __shared__ float red[128];
  float dv = gden[g];
  float inv = (dv > 0.f) ? 1.f / dv : 0.f;
  sh[u] = gfeat_raw[g * 128 + u] * inv;
  __syncthreads();
  float tacc = r1b[u];
  for (int j = 0; j < 128; j++) tacc += sh[j] * r1w[u * 128 + j];
  tacc = fmaxf(tacc, 0.f);
  red[u] = tacc * r2w[u];
  __syncthreads();
  for (int off = 64; off > 0; off >>= 1) {
    if (u < off) red[u] += red[u + off];
    __syncthreads();
  }
  if (u == 0) out[g] = red[0] + r2b[0];
}

extern "C" void kernel_launch(void* const* d_in, const int* in_sizes, int n_in,
                              void* d_out, int out_size, void* d_ws, size_t ws_size,
                              hipStream_t stream) {
  (void)in_sizes; (void)n_in; (void)out_size; (void)ws_size;
  const float* x     = (const float*)d_in[0];
  const int*   ei    = (const int*)d_in[1];
  const int*   batch = (const int*)d_in[2];
  const float* pe    = (const float*)d_in[3];
  const float* niw   = (const float*)d_in[4];
  const float* nib   = (const float*)d_in[5];
  const float* Wq    = (const float*)d_in[6];
  const float* bq    = (const float*)d_in[7];
  const float* Wk    = (const float*)d_in[8];
  const float* bk    = (const float*)d_in[9];
  const float* Wv    = (const float*)d_in[10];
  const float* bv    = (const float*)d_in[11];
  const float* Wsk   = (const float*)d_in[12];
  const float* bsk   = (const float*)d_in[13];
  const float* Wbeta = (const float*)d_in[14];
  const float* g1w   = (const float*)d_in[15];
  const float* g1b   = (const float*)d_in[16];
  const float* g2w   = (const float*)d_in[17];
  const float* g2b   = (const float*)d_in[18];
  const float* r1w   = (const float*)d_in[19];
  const float* r1b   = (const float*)d_in[20];
  const float* r2w   = (const float*)d_in[21];
  const float* r2b   = (const float*)d_in[22];
  float* out = (float*)d_out;

  float* ws = (float*)d_ws;
  float* h     = ws; ws += (size_t)NN * 128;
  float* xrb   = ws; ws += (size_t)NN * 128;
  float* qbbf  = ws; ws += (size_t)NN * 64;   // [N][128] bf16
  float* kvbf  = ws; ws += (size_t)NN * 96;   // [N][384] bytes
  float* hbff  = ws; ws += (size_t)NN * 64;   // [N][128] bf16
  float* Wcatf = ws; ws += 512 * 64;
  float* g1wbf = ws; ws += 128 * 64;
  float* bcat  = ws; ws += 512;
  float* nwT   = ws; ws += 47 * 128;
  float* gx    = ws; ws += NN;
  float* gfeat = ws; ws += GG * 128;
  float* gden  = ws; ws += GG;
  int* row_ptr = (int*)ws;
  int* counts  = row_ptr + (NN + 1);
  int* cursor  = counts + NN;
  int* srcs    = cursor + NN;
  int* gptr    = srcs + EE;
  int* bsum    = gptr + (GG + 1);
  int* bbase   = bsum + 256;

  unsigned short* qbb   = (unsigned short*)qbbf;
  unsigned char*  kvb   = (unsigned char*)kvbf;
  unsigned short* hbf   = (unsigned short*)hbff;
  unsigned short* Wcatb = (unsigned short*)Wcatf;
  unsigned short* g1wb  = (unsigned short*)g1wbf;
  const int* src = ei;
  const int* dst = ei + EE;

  hipMemsetAsync(counts, 0, NN * sizeof(int), stream);
  hipMemsetAsync(gfeat, 0, GG * 128 * sizeof(float), stream);
  pack_weights_kernel<<<(512 * 128 + 255) / 256, 256, 0, stream>>>(
      Wq, Wk, Wv, Wsk, bq, bk, bv, bsk, Wcatb, bcat);
  pack_nwt_kernel<<<(47 * 128 + 255) / 256, 256, 0, stream>>>(niw, nwT);
  pack_g1_kernel<<<(128 * 128 + 255) / 256, 256, 0, stream>>>(g1w, g1wb);
  nodein_kernel<<<12500, 256, 0, stream>>>(x, pe, nwT, nib, h, hbf);
  count_kernel<<<(EE + 255) / 256, 256, 0, stream>>>(dst, counts);
  bsum_kernel<<<NBLK, 256, 0, stream>>>(counts, bsum);
  bscan_kernel<<<1, 64, 0, stream>>>(bsum, bbase);
  rowptr_kernel<<<NBLK, 256, 0, stream>>>(counts, bbase, row_ptr, cursor);
  scatter_kernel<<<(EE + 255) / 256, 256, 0, stream>>>(src, dst, cursor, srcs);
  gptr_kernel<<<1, 128, 0, stream>>>(batch, gptr);

  const int MB = (NN + 127) / 128;  // 391
  for (int l = 0; l < NLAYERS; l++) {
    gemm_mfma_kernel<<<dim3(MB, 8), 256, 0, stream>>>(
        (const bf16*)hbf, (const bf16*)Wcatb, bcat, NN, 0,
        qbb, kvb, xrb, (float*)nullptr);
    attn_beta_kernel<<<12500, 256, 0, stream>>>(
        (const unsigned*)qbb, kvb, row_ptr, srcs, xrb, Wbeta, h, (unsigned*)hbf);
  }

  gemm_mfma_kernel<<<dim3(MB, 2), 256, 0, stream>>>(
      (const bf16*)hbf, (const bf16*)g1wb, g1b, NN, 1,
      (unsigned short*)nullptr, (unsigned char*)nullptr, (float*)nullptr, xrb);
  gate_kernel<<<12500, 256, 0, stream>>>(xrb, g2w, g2b, gx);
  gden_kernel<<<GG, 256, 0, stream>>>(gx, gptr, gden);
  gagg_kernel<<<dim3(GG, 32), 128, 0, stream>>>(gx, h, gptr, gfeat);
  readout_kernel<<<GG, 128, 0, stream>>>(gfeat, gden, r1w, r1b, r2w, r2b, out);
}